// Round 7
// baseline (203.140 us; speedup 1.0000x reference)
//
#include <hip/hip_runtime.h>
#include <hip/hip_bf16.h>

#define NROWS 8192
#define DDIM 64

typedef __attribute__((ext_vector_type(8))) short short8v;
typedef __attribute__((ext_vector_type(4))) float f32x4;

#define K2CONST 2.885390081777927f  /* log2(e)/TAU, TAU=0.5 */
#define EPSC 1e-8f

// ---------------- Kernel 1: row L2-normalize (bf16 P) + diagonals ----------
__global__ __launch_bounds__(256) void k_normalize(
    const float* __restrict__ z, const float* __restrict__ za,
    __hip_bfloat16* __restrict__ Pb,
    float* __restrict__ dI1, float* __restrict__ dI2, float* __restrict__ dX) {
  int wid = (blockIdx.x * blockDim.x + threadIdx.x) >> 6;
  int lane = threadIdx.x & 63;
  if (wid >= NROWS) return;
  float x = z[wid * DDIM + lane];
  float y = za[wid * DDIM + lane];
  float sx = x * x, sy = y * y, sxy = x * y;
  for (int m = 1; m < 64; m <<= 1) {
    sx  += __shfl_xor(sx, m);
    sy  += __shfl_xor(sy, m);
    sxy += __shfl_xor(sxy, m);
  }
  float inx = 1.0f / fmaxf(sqrtf(sx), 1e-12f);
  float iny = 1.0f / fmaxf(sqrtf(sy), 1e-12f);
  Pb[wid * DDIM + lane] = __float2bfloat16(x * inx);
  Pb[(NROWS + wid) * DDIM + lane] = __float2bfloat16(y * iny);
  if (lane == 0) {
    dI1[wid] = expf(sx * inx * inx * 2.0f);   // /TAU = *2
    dI2[wid] = expf(sy * iny * iny * 2.0f);
    dX[wid]  = expf(sxy * inx * iny * 2.0f);
  }
}

// ---------------- Kernel 2: fused gram row-sums + adj-masked sums ----------
// TRANSPOSED mfma: acc = mfma(colfrag, rowfrag) puts 4 consecutive j's for a
// fixed row i in each lane's C-regs -> adj mask is one float4 load per lane.
// Per gram row r: sD[r] = dense sum over all 16384 cols (both quadrants),
//                 sM[r] = adj-masked sum, cnt[r] = mask row degree.
__global__ __launch_bounds__(256) void k_fused(
    const __hip_bfloat16* __restrict__ Pb,
    const float* __restrict__ adj, const float* __restrict__ adj_aug,
    float* __restrict__ sD, float* __restrict__ sM, float* __restrict__ cnt) {
  int wave = threadIdx.x >> 6, lane = threadIdx.x & 63;
  int r_in = lane & 15, kq = lane >> 4;
  int rb = blockIdx.x >> 4;                 // 128 row-blocks of 128 rows
  int cb = blockIdx.x & 15;                 // 16 col-blocks of 512 cols
  int rowbase = rb * 128 + wave * 32;       // this wave: 32 gram rows
  int cbase = cb * 512;
  const float* ADJ = (rowbase < NROWS) ? adj : adj_aug;
  int arow0 = rowbase & (NROWS - 1);
  // lane's adj base: row (arow0 + r_in), col (cbase + kq*4); rt=1 adds 16 rows
  const float* adjp = ADJ + (size_t)(arow0 + r_in) * NROWS + cbase + kq * 4;

  const short8v* P8 = reinterpret_cast<const short8v*>(Pb);
  short8v a0[2], a1[2];                     // row fragments (B operand)
#pragma unroll
  for (int rt = 0; rt < 2; rt++) {
    int row = rowbase + rt * 16 + r_in;
    a0[rt] = P8[row * 8 + kq];
    a1[rt] = P8[row * 8 + kq + 4];
  }
  f32x4 accD0 = (f32x4){0.f,0.f,0.f,0.f}, accM0 = accD0, accC0 = accD0;
  f32x4 accD1 = accD0, accM1 = accD0, accC1 = accD0;

  short8v Ab0, Ab1, Ac0, Ac1; f32x4 Aav0, Aav1;
  short8v Bb0, Bb1, Bc0, Bc1; f32x4 Bav0, Bav1;

#define ISSUE(SET, CT) { \
    int colA_ = cbase + (CT) * 16 + r_in; \
    SET##b0 = P8[colA_ * 8 + kq]; \
    SET##b1 = P8[colA_ * 8 + kq + 4]; \
    SET##c0 = P8[(colA_ + NROWS) * 8 + kq]; \
    SET##c1 = P8[(colA_ + NROWS) * 8 + kq + 4]; \
    SET##av0 = *(const f32x4*)(adjp + (CT) * 16); \
    SET##av1 = *(const f32x4*)(adjp + 131072 + (CT) * 16); }

#define COMPUTE(SET) { \
    f32x4 g0 = (f32x4){0.f,0.f,0.f,0.f}; \
    g0 = __builtin_amdgcn_mfma_f32_16x16x32_bf16(SET##b0, a0[0], g0, 0, 0, 0); \
    g0 = __builtin_amdgcn_mfma_f32_16x16x32_bf16(SET##b1, a1[0], g0, 0, 0, 0); \
    f32x4 g1 = (f32x4){0.f,0.f,0.f,0.f}; \
    g1 = __builtin_amdgcn_mfma_f32_16x16x32_bf16(SET##c0, a0[0], g1, 0, 0, 0); \
    g1 = __builtin_amdgcn_mfma_f32_16x16x32_bf16(SET##c1, a1[0], g1, 0, 0, 0); \
    f32x4 h0 = (f32x4){0.f,0.f,0.f,0.f}; \
    h0 = __builtin_amdgcn_mfma_f32_16x16x32_bf16(SET##b0, a0[1], h0, 0, 0, 0); \
    h0 = __builtin_amdgcn_mfma_f32_16x16x32_bf16(SET##b1, a1[1], h0, 0, 0, 0); \
    f32x4 h1 = (f32x4){0.f,0.f,0.f,0.f}; \
    h1 = __builtin_amdgcn_mfma_f32_16x16x32_bf16(SET##c0, a0[1], h1, 0, 0, 0); \
    h1 = __builtin_amdgcn_mfma_f32_16x16x32_bf16(SET##c1, a1[1], h1, 0, 0, 0); \
    f32x4 t0, t1; \
    _Pragma("unroll") \
    for (int c = 0; c < 4; c++) { \
      t0[c] = exp2f(g0[c] * K2CONST) + exp2f(g1[c] * K2CONST); \
      t1[c] = exp2f(h0[c] * K2CONST) + exp2f(h1[c] * K2CONST); \
    } \
    accD0 += t0; accM0 += SET##av0 * t0; accC0 += SET##av0; \
    accD1 += t1; accM1 += SET##av1 * t1; accC1 += SET##av1; }

  ISSUE(A, 0);
  for (int ct = 0; ct < 32; ct += 2) {
    ISSUE(B, ct + 1);
    COMPUTE(A);
    ISSUE(A, ct + 2);     // ct+2==32 on last iter: dummy read, in-bounds of ws/adj
    COMPUTE(B);
  }
#undef ISSUE
#undef COMPUTE

  // horizontal sum over the 4 j's per lane, then reduce over kq (lane bits 4,5)
  float rD0 = accD0[0] + accD0[1] + accD0[2] + accD0[3];
  float rM0 = accM0[0] + accM0[1] + accM0[2] + accM0[3];
  float rC0 = accC0[0] + accC0[1] + accC0[2] + accC0[3];
  float rD1 = accD1[0] + accD1[1] + accD1[2] + accD1[3];
  float rM1 = accM1[0] + accM1[1] + accM1[2] + accM1[3];
  float rC1 = accC1[0] + accC1[1] + accC1[2] + accC1[3];
#pragma unroll
  for (int m = 16; m < 64; m <<= 1) {
    rD0 += __shfl_xor(rD0, m); rM0 += __shfl_xor(rM0, m); rC0 += __shfl_xor(rC0, m);
    rD1 += __shfl_xor(rD1, m); rM1 += __shfl_xor(rM1, m); rC1 += __shfl_xor(rC1, m);
  }
  if (kq == 0) {
    int row0 = rowbase + r_in;
    atomicAdd(&sD[row0], rD0); atomicAdd(&sM[row0], rM0); atomicAdd(&cnt[row0], rC0);
    int row1 = rowbase + 16 + r_in;
    atomicAdd(&sD[row1], rD1); atomicAdd(&sM[row1], rM1); atomicAdd(&cnt[row1], rC1);
  }
}

// ---------------- Final: per-row loss, partial sums ----------------
__global__ __launch_bounds__(256) void k_final_partial(
    const float* __restrict__ sD, const float* __restrict__ sM,
    const float* __restrict__ dI1, const float* __restrict__ dI2,
    const float* __restrict__ dX,
    const float* __restrict__ cnt, float* __restrict__ acc) {
  int i = blockIdx.x * blockDim.x + threadIdx.x;  // 32 blocks x 256 = 8192
  float pos1 = dX[i] + sM[i];
  float den1 = sD[i] - dI1[i];
  float l1 = logf(pos1 / (den1 + EPSC) + EPSC) / (2.0f * cnt[i] + 1.0f);
  float pos2 = dX[i] + sM[NROWS + i];
  float den2 = sD[NROWS + i] - dI2[i];
  float l2 = logf(pos2 / (den2 + EPSC) + EPSC) / (2.0f * cnt[NROWS + i] + 1.0f);
  float local = l1 + l2;
#pragma unroll
  for (int m = 1; m < 64; m <<= 1) local += __shfl_xor(local, m);
  if ((threadIdx.x & 63) == 0) atomicAdd(acc, local);
}

__global__ void k_finalize(const float* __restrict__ acc, float* __restrict__ out) {
  out[0] = -acc[0] * (0.5f / (float)NROWS);
}

extern "C" void kernel_launch(void* const* d_in, const int* in_sizes, int n_in,
                              void* d_out, int out_size, void* d_ws, size_t ws_size,
                              hipStream_t stream) {
  const float* z       = (const float*)d_in[0];
  const float* za      = (const float*)d_in[1];
  const float* adj     = (const float*)d_in[2];
  const float* adj_aug = (const float*)d_in[3];

  float* ws = (float*)d_ws;
  __hip_bfloat16* Pb = (__hip_bfloat16*)ws;   // 16384*64 bf16 = 524288 f32 slots
  float* Z0   = ws + 524288;    // zeroed region: 3*16384 + 1 floats
  float* sD   = Z0;             // 16384
  float* sM   = Z0 + 16384;     // 16384
  float* cnt  = Z0 + 32768;     // 16384
  float* acc  = Z0 + 49152;     // 1
  float* dI1  = Z0 + 49153;     // 8192
  float* dI2  = dI1 + 8192;     // 8192
  float* dX   = dI2 + 8192;     // 8192

  hipMemsetAsync(Z0, 0, 49153 * sizeof(float), stream);

  k_normalize<<<2048, 256, 0, stream>>>(z, za, Pb, dI1, dI2, dX);
  k_fused<<<2048, 256, 0, stream>>>(Pb, adj, adj_aug, sD, sM, cnt);
  k_final_partial<<<32, 256, 0, stream>>>(sD, sM, dI1, dI2, dX, cnt, acc);
  k_finalize<<<1, 1, 0, stream>>>(acc, (float*)d_out);
}